// Round 11
// baseline (244.771 us; speedup 1.0000x reference)
//
#include <hip/hip_runtime.h>
#include <hip/hip_bf16.h>
#include <math.h>

#define EMBED 512
#define HEADS 8
#define HD    64
#define FFN_  2048
#define NB    4
#define LSEQ  2048
#define MROWS (NB*LSEQ)    // 8192
#define BHN   (NB*HEADS)   // 32

typedef __attribute__((ext_vector_type(8))) short bf16x8;
typedef __attribute__((ext_vector_type(4))) float f32x4;
#define MFMA16(a,b,c) __builtin_amdgcn_mfma_f32_16x16x32_bf16(a,b,c,0,0,0)

__device__ __forceinline__ unsigned short f2bf(float f) {
    unsigned int u = __float_as_uint(f);
    u += 0x7fff + ((u >> 16) & 1);          // round-to-nearest-even
    return (unsigned short)(u >> 16);
}
__device__ __forceinline__ float bf2f(unsigned short u) {
    return __uint_as_float(((unsigned int)u) << 16);
}
__device__ __forceinline__ unsigned int cvt_pk_bf16(float lo, float hi) {
    unsigned int r;
    asm("v_cvt_pk_bf16_f32 %0, %1, %2" : "=v"(r) : "v"(lo), "v"(hi));
    return r;
}
__device__ __forceinline__ void gl_lds16(const unsigned short* g, unsigned short* l) {
    __builtin_amdgcn_global_load_lds(
        (const __attribute__((address_space(1))) unsigned int*)g,
        (__attribute__((address_space(3))) unsigned int*)l, 16, 0, 0);
}
// fast tanh-gelu
__device__ __forceinline__ float gelu_f(float x) {
    float u = x * fmaf(x * x, 0.044715f, 1.0f) * 0.7978845608f;
    float a = fminf(fmaxf(u * 2.885390082f, -30.f), 30.f);   // 2*log2e*u
    float t = __builtin_amdgcn_exp2f(a);
    return x * t * __builtin_amdgcn_rcpf(t + 1.0f);
}
// bijective XCD swizzle (nwg % 8 == 0 everywhere here)
__device__ __forceinline__ void xcd_swz(int& bx, int& by, int gx, int gy) {
    int nwg = gx * gy;
    int lid = by * gx + bx;
    int cpx = nwg >> 3;
    int swz = (lid & 7) * cpx + (lid >> 3);
    bx = swz % gx;
    by = swz / gx;
}

// ---------------- merged prep kernel ----------------
__device__ __forceinline__ void wtrans_body(const float* __restrict__ in,
                                            unsigned short* __restrict__ out,
                                            int K, int N, int bx, int by,
                                            float (*tile)[33]) {
    const int k0 = by * 32, n0 = bx * 32;
    const int t = threadIdx.x;
    const int r = t >> 3, c = (t & 7) * 4;
    float4 v = *reinterpret_cast<const float4*>(&in[(size_t)(k0 + r) * N + n0 + c]);
    tile[r][c] = v.x; tile[r][c + 1] = v.y; tile[r][c + 2] = v.z; tile[r][c + 3] = v.w;
    __syncthreads();
    unsigned short tmp[4] = {f2bf(tile[c + 0][r]), f2bf(tile[c + 1][r]),
                             f2bf(tile[c + 2][r]), f2bf(tile[c + 3][r])};
    *reinterpret_cast<uint2*>(&out[(size_t)(n0 + r) * K + k0 + c]) =
        *reinterpret_cast<uint2*>(tmp);
}

__global__ __launch_bounds__(256) void prep(
    const float* __restrict__ x, unsigned short* __restrict__ xb,
    const float* __restrict__ qkv_w, unsigned short* __restrict__ qkv_wT,
    const float* __restrict__ out_w, unsigned short* __restrict__ out_wT,
    const float* __restrict__ w1, unsigned short* __restrict__ w1T,
    const float* __restrict__ w2, unsigned short* __restrict__ w2T)
{
    __shared__ float tile[32][33];
    const int blk = blockIdx.x;
    if (blk < 2048) {
        int i = (blk * 256 + threadIdx.x) * 8;
        float4 a = *reinterpret_cast<const float4*>(&x[i]);
        float4 b = *reinterpret_cast<const float4*>(&x[i + 4]);
        unsigned short t8[8] = {f2bf(a.x), f2bf(a.y), f2bf(a.z), f2bf(a.w),
                                f2bf(b.x), f2bf(b.y), f2bf(b.z), f2bf(b.w)};
        *reinterpret_cast<uint4*>(&xb[i]) = *reinterpret_cast<uint4*>(t8);
    } else if (blk < 2816) {
        int i = blk - 2048; wtrans_body(qkv_w, qkv_wT, 512, 1536, i % 48, i / 48, tile);
    } else if (blk < 3072) {
        int i = blk - 2816; wtrans_body(out_w, out_wT, 512, 512, i % 16, i / 16, tile);
    } else if (blk < 4096) {
        int i = blk - 3072; wtrans_body(w1, w1T, 512, 2048, i % 64, i / 64, tile);
    } else {
        int i = blk - 4096; wtrans_body(w2, w2T, 2048, 512, i % 16, i / 16, tile);
    }
}

// ---------------- bf16 MFMA GEMM, 128x128 tile, dbuf + T2 XOR swizzle ----
// MODE 0: scatter q/k head-major; V written transposed + pos-permuted
//         (exactly the layout round-9's vtransp produced:
//          VTp[bh][d][tile + pos], pos = (lt&32) + ((lt&15)<<1) + ((lt>>4)&1))
// MODE 2: bf16 out = gelu(val)
template<int MODE>
__global__ __launch_bounds__(256) void gemm_bf16(
    const unsigned short* __restrict__ A, const unsigned short* __restrict__ WT,
    const float* __restrict__ bias,
    void* __restrict__ o0, void* __restrict__ o1, void* __restrict__ o2,
    int M, int N, int K)
{
    __shared__ unsigned short As[2][128 * 64];
    __shared__ unsigned short Bs[2][128 * 64];
    int bx = blockIdx.x, by = blockIdx.y;
    xcd_swz(bx, by, gridDim.x, gridDim.y);
    const int t = threadIdx.x;
    const int m0 = by * 128, n0 = bx * 128;
    const int w = t >> 6, lane = t & 63;
    const int wm = (w >> 1) * 64, wn = (w & 1) * 64;
    const int lr = lane & 15, lk = (lane >> 4) * 8;
    const int rb = (lane >> 4) * 4;
    const int srow = lane >> 3;
    const int scol = (((lane & 7) ^ (srow & 7)) * 8);   // pre-swizzled source col
    const int rxor = (lr & 7) * 8;                      // read-side XOR

    f32x4 zero = {0.f, 0.f, 0.f, 0.f};
    f32x4 acc[4][4];
    #pragma unroll
    for (int i = 0; i < 4; ++i)
        #pragma unroll
        for (int j = 0; j < 4; ++j) acc[i][j] = zero;

    auto stage = [&](int buf, int k0) {
        #pragma unroll
        for (int i = 0; i < 4; ++i) {
            const int seg = w * 4 + i;
            const int r = seg * 8 + srow;
            gl_lds16(A  + (size_t)(m0 + r) * K + k0 + scol, &As[buf][seg * 512 + lane * 8]);
            gl_lds16(WT + (size_t)(n0 + r) * K + k0 + scol, &Bs[buf][seg * 512 + lane * 8]);
        }
    };

    const int nk = K >> 6;
    stage(0, 0);
    for (int ti = 0; ti < nk; ++ti) {
        if (ti + 1 < nk) {
            stage((ti + 1) & 1, (ti + 1) << 6);
            asm volatile("s_waitcnt vmcnt(8)" ::: "memory");
        } else {
            asm volatile("s_waitcnt vmcnt(0)" ::: "memory");
        }
        __builtin_amdgcn_s_barrier();
        const unsigned short* as = As[ti & 1];
        const unsigned short* bs = Bs[ti & 1];
        #pragma unroll
        for (int kk = 0; kk < 2; ++kk) {
            bf16x8 a[4], b[4];
            #pragma unroll
            for (int i = 0; i < 4; ++i)
                a[i] = *reinterpret_cast<const bf16x8*>(
                    &as[(wm + i * 16 + lr) * 64 + ((kk * 32 + lk) ^ rxor)]);
            #pragma unroll
            for (int j = 0; j < 4; ++j)
                b[j] = *reinterpret_cast<const bf16x8*>(
                    &bs[(wn + j * 16 + lr) * 64 + ((kk * 32 + lk) ^ rxor)]);
            #pragma unroll
            for (int i = 0; i < 4; ++i)
                #pragma unroll
                for (int j = 0; j < 4; ++j)
                    acc[i][j] = MFMA16(a[i], b[j], acc[i][j]);
        }
        __builtin_amdgcn_s_barrier();
    }

    #pragma unroll
    for (int i = 0; i < 4; ++i) {
        #pragma unroll
        for (int j = 0; j < 4; ++j) {
            const int n = n0 + wn + j * 16 + lr;
            const float bv = bias[n];
            #pragma unroll
            for (int r = 0; r < 4; ++r) {
                const int m = m0 + wm + i * 16 + rb + r;
                float val = acc[i][j][r] + bv;
                if (MODE == 0) {
                    const int which = n >> 9, nn = n & 511, hs = nn >> 6, d = nn & 63;
                    const int bh = (m >> 11) * 8 + hs, l = m & 2047;
                    if (which == 2) {
                        const int lt = l & 63;
                        const int pos = (lt & 32) + ((lt & 15) << 1) + ((lt >> 4) & 1);
                        ((unsigned short*)o2)[((size_t)bh * HD + d) * LSEQ +
                                              (l - lt) + pos] = f2bf(val);
                    } else {
                        unsigned short* p = (which == 0) ? (unsigned short*)o0
                                                         : (unsigned short*)o1;
                        p[((size_t)bh * LSEQ + l) * HD + d] = f2bf(val);
                    }
                } else {
                    size_t idx = (size_t)m * N + n;
                    ((unsigned short*)o0)[idx] = f2bf(gelu_f(val));
                }
            }
        }
    }
}

// ---------------- bf16 MFMA GEMM, 64x64 tile, dbuf + T2 swizzle, N=512 GEMMs ----
// res bf16, out bf16 (out-proj + residual ; FFN2 + residual)
__global__ __launch_bounds__(256) void gemm64(
    const unsigned short* __restrict__ A, const unsigned short* __restrict__ WT,
    const float* __restrict__ bias, const unsigned short* __restrict__ res,
    unsigned short* __restrict__ out, int M, int N, int K)
{
    __shared__ unsigned short As[2][64 * 64];
    __shared__ unsigned short Bs[2][64 * 64];
    int bx = blockIdx.x, by = blockIdx.y;
    xcd_swz(bx, by, gridDim.x, gridDim.y);
    const int t = threadIdx.x;
    const int m0 = by * 64, n0 = bx * 64;
    const int w = t >> 6, lane = t & 63;
    const int wm = (w >> 1) * 32, wn = (w & 1) * 32;
    const int lr = lane & 15, lk = (lane >> 4) * 8;
    const int rb = (lane >> 4) * 4;
    const int srow = t >> 3;
    const int scol = (((t & 7) ^ (srow & 7)) * 8);
    const int rxor = (lr & 7) * 8;

    f32x4 zero = {0.f, 0.f, 0.f, 0.f};
    f32x4 acc[2][2];
    #pragma unroll
    for (int i = 0; i < 2; ++i)
        #pragma unroll
        for (int j = 0; j < 2; ++j) acc[i][j] = zero;

    auto stage = [&](int buf, int k0) {
        gl_lds16(A  + (size_t)(m0 + srow)      * K + k0 + scol, &As[buf][t * 8]);
        gl_lds16(A  + (size_t)(m0 + 32 + srow) * K + k0 + scol, &As[buf][2048 + t * 8]);
        gl_lds16(WT + (size_t)(n0 + srow)      * K + k0 + scol, &Bs[buf][t * 8]);
        gl_lds16(WT + (size_t)(n0 + 32 + srow) * K + k0 + scol, &Bs[buf][2048 + t * 8]);
    };

    const int nk = K >> 6;
    stage(0, 0);
    for (int ti = 0; ti < nk; ++ti) {
        if (ti + 1 < nk) {
            stage((ti + 1) & 1, (ti + 1) << 6);
            asm volatile("s_waitcnt vmcnt(4)" ::: "memory");
        } else {
            asm volatile("s_waitcnt vmcnt(0)" ::: "memory");
        }
        __builtin_amdgcn_s_barrier();
        const unsigned short* as = As[ti & 1];
        const unsigned short* bs = Bs[ti & 1];
        #pragma unroll
        for (int kk = 0; kk < 2; ++kk) {
            bf16x8 a[2], b[2];
            #pragma unroll
            for (int i = 0; i < 2; ++i)
                a[i] = *reinterpret_cast<const bf16x8*>(
                    &as[(wm + i * 16 + lr) * 64 + ((kk * 32 + lk) ^ rxor)]);
            #pragma unroll
            for (int j = 0; j < 2; ++j)
                b[j] = *reinterpret_cast<const bf16x8*>(
                    &bs[(wn + j * 16 + lr) * 64 + ((kk * 32 + lk) ^ rxor)]);
            #pragma unroll
            for (int i = 0; i < 2; ++i)
                #pragma unroll
                for (int j = 0; j < 2; ++j)
                    acc[i][j] = MFMA16(a[i], b[j], acc[i][j]);
        }
        __builtin_amdgcn_s_barrier();
    }

    #pragma unroll
    for (int i = 0; i < 2; ++i) {
        #pragma unroll
        for (int j = 0; j < 2; ++j) {
            const int n = n0 + wn + j * 16 + lr;
            const float bv = bias[n];
            #pragma unroll
            for (int r = 0; r < 4; ++r) {
                const int m = m0 + wm + i * 16 + rb + r;
                size_t idx = (size_t)m * N + n;
                out[idx] = f2bf(acc[i][j][r] + bv + bf2f(res[idx]));
            }
        }
    }
}

// ---------------- MFMA flash attention: key-split, 8 waves, 32 rows/wave ----
// (byte-identical to the round-9 passing version)
__global__ __launch_bounds__(512) void attn_mfma(
    const unsigned short* __restrict__ Q, const unsigned short* __restrict__ K,
    const unsigned short* __restrict__ VTp, const int* __restrict__ mask,
    unsigned short* __restrict__ out)
{
    __shared__ __align__(16) char smem[54272];
    unsigned short* const KsS = (unsigned short*)smem;            // 2 x 4096 shorts
    unsigned short* const VsS = (unsigned short*)(smem + 16384);  // 2 x 4096 shorts
    unsigned short* const PsS = (unsigned short*)(smem + 32768);  // 128 x 72 shorts
    unsigned short* const kbl = (unsigned short*)(smem + 51200);  // 1536 bf16
    float* const red = (float*)smem;                              // reduce (dead K/V/Ps)

    int bx = blockIdx.x, by = blockIdx.y;
    xcd_swz(bx, by, 16, 32);
    const int qt = bx, bh = by;
    const int b = bh >> 3, hh = bh & 7;
    const int t = threadIdx.x, w = t >> 6, lane = t & 63;
    const int lr = lane & 15, hi = lane >> 4;
    const int kh = w >> 2, wr = (w & 3) * 32;   // key-half, row offset
    const int qr0 = qt * 128;
    const int c = qr0 >> 9;
    const int kstart = max(0, (c - 1) * 512), kend = min(LSEQ, (c + 2) * 512);
    const int nk = kend - kstart, nkt = nk >> 6;

    const float C1  = 0.18033688f;   // 0.125 * log2(e)
    const float KB0 = -14.4269504f;  // -MFIX(=10) * log2(e)

    const int srow = t >> 3, sslot = t & 7;
    const unsigned short* ksrc = K   + ((size_t)bh * LSEQ + kstart + srow) * HD
                                     + ((sslot ^ (srow & 7)) * 8);
    const unsigned short* vsrc = VTp + ((size_t)bh * HD + srow) * LSEQ + kstart
                                     + ((sslot ^ (srow & 7)) * 8);

    bf16x8 qf[2][2];
    #pragma unroll
    for (int fr = 0; fr < 2; ++fr)
        #pragma unroll
        for (int kk = 0; kk < 2; ++kk)
            qf[fr][kk] = *reinterpret_cast<const bf16x8*>(
                &Q[((size_t)bh * LSEQ + qr0 + wr + fr * 16 + lr) * HD + kk * 32 + hi * 8]);

    for (int i = t; i < nk; i += 512)
        kbl[i] = mask[b * LSEQ + kstart + i] ? f2bf(-1e30f) : f2bf(KB0);

    f32x4 zero = {0.f, 0.f, 0.f, 0.f};
    f32x4 acc[2][4];
    float lsum[2][4];
    #pragma unroll
    for (int fr = 0; fr < 2; ++fr) {
        #pragma unroll
        for (int j = 0; j < 4; ++j) acc[fr][j] = zero;
        #pragma unroll
        for (int r = 0; r < 4; ++r) lsum[fr][r] = 0.f;
    }

    gl_lds16(ksrc, KsS + t * 8);
    gl_lds16(vsrc, VsS + t * 8);
    __syncthreads();

    const int kxor = (lr & 7) * 8;
    for (int ti = 0; ti < nkt; ++ti) {
        if (ti + 1 < nkt) {
            const int off = (ti + 1) * 64;
            gl_lds16(ksrc + (size_t)off * HD, KsS + ((ti + 1) & 1) * 4096 + t * 8);
            gl_lds16(vsrc + off,              VsS + ((ti + 1) & 1) * 4096 + t * 8);
            asm volatile("s_waitcnt vmcnt(2)" ::: "memory");
        } else {
            asm volatile("s_waitcnt vmcnt(0)" ::: "memory");
        }
        __builtin_amdgcn_s_barrier();
        const unsigned short* ks = KsS + (ti & 1) * 4096;
        const unsigned short* vs = VsS + (ti & 1) * 4096;
        const int kg0 = ti * 64;

        f32x4 s[2][2];
        #pragma unroll
        for (int fr = 0; fr < 2; ++fr)
            #pragma unroll
            for (int j = 0; j < 2; ++j) s[fr][j] = zero;
        #pragma unroll
        for (int kk = 0; kk < 2; ++kk) {
            #pragma unroll
            for (int j = 0; j < 2; ++j) {
                bf16x8 bk = *reinterpret_cast<const bf16x8*>(
                    &ks[(kh * 32 + j * 16 + lr) * 64 + (((kk * 4 + hi) * 8) ^ kxor)]);
                s[0][j] = MFMA16(qf[0][kk], bk, s[0][j]);
                s[1][j] = MFMA16(qf[1][kk], bk, s[1][j]);
            }
        }
        const float kb0 = bf2f(kbl[kg0 + kh * 32 + lr]);
        const float kb1 = bf2f(kbl[kg0 + kh * 32 + 16 + lr]);
        #pragma unroll
        for (int fr = 0; fr < 2; ++fr) {
            #pragma unroll
            for (int r = 0; r < 4; ++r) {
                float p0 = __builtin_amdgcn_exp2f(fmaf(s[fr][0][r], C1, kb0));
                float p1 = __builtin_amdgcn_exp2f(fmaf(s[fr][1][r], C1, kb1));
                lsum[fr][r] += p0 + p1;
                const int row = wr + fr * 16 + hi * 4 + r;
                *reinterpret_cast<unsigned int*>(&PsS[row * 72 + kh * 32 + lr * 2]) =
                    cvt_pk_bf16(p0, p1);
            }
        }
        #pragma unroll
        for (int fr = 0; fr < 2; ++fr) {
            bf16x8 pa = *reinterpret_cast<const bf16x8*>(
                &PsS[(wr + fr * 16 + lr) * 72 + kh * 32 + hi * 8]);
            #pragma unroll
            for (int j = 0; j < 4; ++j) {
                bf16x8 bv = *reinterpret_cast<const bf16x8*>(
                    &vs[(j * 16 + lr) * 64 + (((kh * 4 + hi) * 8) ^ kxor)]);
                acc[fr][j] = MFMA16(pa, bv, acc[fr][j]);
            }
        }
        __builtin_amdgcn_s_barrier();
    }

    __syncthreads();
    const int rid = (w & 3) * 64 + lane;
    if (w >= 4) {
        #pragma unroll
        for (int fr = 0; fr < 2; ++fr)
            #pragma unroll
            for (int j = 0; j < 4; ++j)
                #pragma unroll
                for (int r = 0; r < 4; ++r)
                    red[((fr * 4 + j) * 4 + r) * 256 + rid] = acc[fr][j][r];
        #pragma unroll
        for (int fr = 0; fr < 2; ++fr)
            #pragma unroll
            for (int r = 0; r < 4; ++r)
                red[(32 + fr * 4 + r) * 256 + rid] = lsum[fr][r];
    }
    __syncthreads();
    if (w < 4) {
        #pragma unroll
        for (int fr = 0; fr < 2; ++fr)
            #pragma unroll
            for (int j = 0; j < 4; ++j)
                #pragma unroll
                for (int r = 0; r < 4; ++r)
                    acc[fr][j][r] += red[((fr * 4 + j) * 4 + r) * 256 + rid];
        #pragma unroll
        for (int fr = 0; fr < 2; ++fr)
            #pragma unroll
            for (int r = 0; r < 4; ++r)
                lsum[fr][r] += red[(32 + fr * 4 + r) * 256 + rid];

        float linv[2][4];
        #pragma unroll
        for (int fr = 0; fr < 2; ++fr)
            #pragma unroll
            for (int r = 0; r < 4; ++r) {
                float v = lsum[fr][r];
                v += __shfl_xor(v, 1, 16);
                v += __shfl_xor(v, 2, 16);
                v += __shfl_xor(v, 4, 16);
                v += __shfl_xor(v, 8, 16);
                linv[fr][r] = 1.0f / v;
            }
        #pragma unroll
        for (int fr = 0; fr < 2; ++fr)
            #pragma unroll
            for (int j = 0; j < 4; ++j)
                #pragma unroll
                for (int r = 0; r < 4; ++r) {
                    const int l = qr0 + wr + fr * 16 + hi * 4 + r;
                    const int d = j * 16 + lr;
                    out[((size_t)(b * LSEQ + l)) * EMBED + hh * HD + d] =
                        f2bf(acc[fr][j][r] * linv[fr][r]);
                }
    }
}

// ---------------- layernorm, one wave per row, bf16 in ----------------
// OUTF32=0: bf16 out ; OUTF32=1: fp32 out
template<int OUTF32>
__global__ __launch_bounds__(256) void ln_row(
    const unsigned short* __restrict__ in, const float* __restrict__ g,
    const float* __restrict__ bt, void* __restrict__ outp)
{
    const int t = threadIdx.x, lane = t & 63;
    const int row = blockIdx.x * 4 + (t >> 6);
    uint4 raw = *reinterpret_cast<const uint4*>(&in[(size_t)row * EMBED + lane * 8]);
    float v[8];
    const unsigned int* rw = reinterpret_cast<const unsigned int*>(&raw);
    #pragma unroll
    for (int i = 0; i < 4; ++i) {
        v[2 * i]     = __uint_as_float(rw[i] << 16);
        v[2 * i + 1] = __uint_as_float(rw[i] & 0xffff0000u);
    }
    float s = 0.f, ss = 0.f;
    #pragma unroll
    for (int i = 0; i < 8; ++i) { s += v[i]; ss += v[i] * v[i]; }
    #pragma unroll
    for (int off = 1; off < 64; off <<= 1) {
        s  += __shfl_xor(s, off);
        ss += __shfl_xor(ss, off);
    }
    const float mu = s * (1.0f / EMBED);
    const float var = ss * (1.0f / EMBED) - mu * mu;
    const float rs = rsqrtf(var + 1e-5f);
    float4 g0 = *reinterpret_cast<const float4*>(&g[lane * 8]);
    float4 g1 = *reinterpret_cast<const float4*>(&g[lane * 8 + 4]);
    float4 b0 = *reinterpret_cast<const float4*>(&bt[lane * 8]);
    float4 b1 = *reinterpret_cast<const float4*>(&bt[lane * 8 + 4]);
    float gg[8] = {g0.x, g0.y, g0.z, g0.w, g1.x, g1.y, g1.z, g1.w};
    float bb[8] = {b0.x, b0.y, b0.z, b0.w, b1.x, b1.y, b1.z, b1.w};
    float o[8];
    #pragma unroll
    for (int i = 0; i < 8; ++i) o[i] = (v[i] - mu) * rs * gg[i] + bb[i];
    if (OUTF32) {
        float* op = (float*)outp + (size_t)row * EMBED + lane * 8;
        *reinterpret_cast<float4*>(op)     = make_float4(o[0], o[1], o[2], o[3]);
        *reinterpret_cast<float4*>(op + 4) = make_float4(o[4], o[5], o[6], o[7]);
    } else {
        unsigned short ob[8];
        #pragma unroll
        for (int i = 0; i < 8; ++i) ob[i] = f2bf(o[i]);
        *reinterpret_cast<uint4*>((unsigned short*)outp + (size_t)row * EMBED + lane * 8) =
            *reinterpret_cast<uint4*>(ob);
    }
}

extern "C" void kernel_launch(void* const* d_in, const int* in_sizes, int n_in,
                              void* d_out, int out_size, void* d_ws, size_t ws_size,
                              hipStream_t stream) {
    const float* x      = (const float*)d_in[0];
    const int*   mask   = (const int*)  d_in[1];
    const float* qkv_w  = (const float*)d_in[2];
    const float* qkv_b  = (const float*)d_in[3];
    const float* out_w  = (const float*)d_in[4];
    const float* out_b  = (const float*)d_in[5];
    const float* ffn_w1 = (const float*)d_in[6];
    const float* ffn_b1 = (const float*)d_in[7];
    const float* ffn_w2 = (const float*)d_in[8];
    const float* ffn_b2 = (const float*)d_in[9];
    const float* ln1_g  = (const float*)d_in[10];
    const float* ln1_b  = (const float*)d_in[11];
    const float* ln2_g  = (const float*)d_in[12];
    const float* ln2_b  = (const float*)d_in[13];

    char* wsb = (char*)d_ws;
    unsigned short* qkv_wT = (unsigned short*)(wsb + 0);          // 1.5 MB
    unsigned short* out_wT = (unsigned short*)(wsb + 1572864);    // 0.5 MB
    unsigned short* w1T    = (unsigned short*)(wsb + 2097152);    // 2 MB
    unsigned short* w2T    = (unsigned short*)(wsb + 4194304);    // 2 MB
    unsigned short* xb     = (unsigned short*)(wsb + 6291456);    // A: 8 MB
    unsigned short* qb     = (unsigned short*)(wsb + 14680064);   // B: 8 MB
    unsigned short* kbuf   = (unsigned short*)(wsb + 23068672);   // C: 8 MB
    unsigned short* am     = (unsigned short*)(wsb + 31457280);   // D: 8 MB (attn out)
    unsigned short* y      = (unsigned short*)(wsb + 39845888);   // E: 8 MB (bf16)
    unsigned short* h      = (unsigned short*)(wsb + 47185920);   // F: 32 MB
    unsigned short* zb     = (unsigned short*)(wsb + 80740352);   // 8 MB (bf16)
    unsigned short* vTp    = (unsigned short*)(wsb + 97058816);   // G: 8 MB
    unsigned short* xlnb   = vTp;    // G reused after attn (vTp dead post-attn)

    // 0) prep: x->bf16 + 4 weight transposes (merged)
    prep<<<5120, 256, 0, stream>>>(x, xb, qkv_w, qkv_wT, out_w, out_wT,
                                   ffn_w1, w1T, ffn_w2, w2T);
    // 1) QKV projection -> q,k head-major; V directly transposed+permuted
    gemm_bf16<0><<<dim3(1536 / 128, MROWS / 128), 256, 0, stream>>>(
        xb, qkv_wT, qkv_b, qb, kbuf, vTp, MROWS, 1536, 512);
    // 2) attention -> am (merged bf16)
    attn_mfma<<<dim3(LSEQ / 128, BHN), 512, 0, stream>>>(qb, kbuf, vTp, mask, am);
    // 3) out projection + residual(xb bf16) -> y bf16
    gemm64<<<dim3(EMBED / 64, MROWS / 64), 256, 0, stream>>>(
        am, out_wT, out_b, xb, y, MROWS, EMBED, 512);
    // 4) LN1 -> xlnb bf16 (G; vTp dead after attn)
    ln_row<0><<<MROWS / 4, 256, 0, stream>>>(y, ln1_g, ln1_b, xlnb);
    // 5) FFN1 + GELU -> h bf16
    gemm_bf16<2><<<dim3(FFN_ / 128, MROWS / 128), 256, 0, stream>>>(
        xlnb, w1T, ffn_b1, h, nullptr, nullptr, MROWS, FFN_, 512);
    // 6) FFN2 + residual(xlnb bf16) -> zb bf16
    gemm64<<<dim3(EMBED / 64, MROWS / 64), 256, 0, stream>>>(
        h, w2T, ffn_b2, xlnb, zb, MROWS, EMBED, FFN_);
    // 7) LN2 -> out fp32
    ln_row<1><<<MROWS / 4, 256, 0, stream>>>(zb, ln2_g, ln2_b, (float*)d_out);
}